// Round 6
// baseline (174.449 us; speedup 1.0000x reference)
//
#include <hip/hip_runtime.h>
#include <math.h>

#define B_ 16
#define N_ 4096
#define D_ 512
#define M_ 64
#define MD 32768   // M_*D_

typedef __attribute__((ext_vector_type(4))) float f32x4;
typedef __attribute__((ext_vector_type(8))) short short8;

// ---- workspace layout (float offsets) ----
#define OFF_PSUM   0          // [16][32][2][512] pooling sum partials (524288)
#define OFF_PMAXP  524288     // [16][32][2][512] pooling max partials (524288)
#define OFF_CTXB   1048576    // bf16 [16][1024] ctx (8192 floats)
#define OFF_P      1056768    // fp32 P[b][m*512+d] natural (524288)
#define OFF_CB     1581056    // [16][64]
#define OFF_GMAX   1582080    // [16][64]
#define OFF_GINV   1583104    // [16][64]
#define OFF_TPMAX  1584128    // [1024][256] (262144)
#define OFF_TPSUM  1846272    // [1024][256] (262144)
#define OFF_QB     2108416    // bf16 [16][64][512] (262144 floats)
#define OFF_XB     2370560    // bf16 [16][4096][512] (16777216 floats)
#define OFF_LOGITS 19147776   // [16][4096][64] (4194304)
// total = 23342080 floats = 93.4 MB (ws is ~512 MB per harness fill size)

__device__ __forceinline__ unsigned short f2bf(float f) {
    unsigned int u = __float_as_uint(f);
    u += 0x7fffu + ((u >> 16) & 1u);   // round-to-nearest-even
    return (unsigned short)(u >> 16);
}

// ---- K1: pooling partials + bf16 X emit. grid 512 (b*32+nc), block 256 ----
// thread: cols 4c..4c+3 (c=t&127), rows nc*128 + 2*i + p (p=t>>7), i<64
__global__ __launch_bounds__(256) void k_pool(const float* __restrict__ X, float* __restrict__ ws) {
    int b = blockIdx.x >> 5, nc = blockIdx.x & 31, t = threadIdx.x;
    int c = t & 127, p = t >> 7;
    const float4* X4 = (const float4*)X;
    ushort4* Xb4 = (ushort4*)(ws + OFF_XB);
    float4 s = make_float4(0.f, 0.f, 0.f, 0.f);
    float4 mx = make_float4(-INFINITY, -INFINITY, -INFINITY, -INFINITY);
    int rowbase = b * N_ + nc * 128 + p;
    for (int i = 0; i < 64; i++) {
        int n = rowbase + 2 * i;
        float4 v = X4[n * 128 + c];
        s.x += v.x; s.y += v.y; s.z += v.z; s.w += v.w;
        mx.x = fmaxf(mx.x, v.x); mx.y = fmaxf(mx.y, v.y);
        mx.z = fmaxf(mx.z, v.z); mx.w = fmaxf(mx.w, v.w);
        ushort4 w;
        w.x = f2bf(v.x); w.y = f2bf(v.y); w.z = f2bf(v.z); w.w = f2bf(v.w);
        Xb4[n * 128 + c] = w;
    }
    int slot = (b * 64 + nc * 2 + p) * 128 + c;   // float4 units
    ((float4*)(ws + OFF_PSUM))[slot] = s;
    ((float4*)(ws + OFF_PMAXP))[slot] = mx;
}

// ---- K1b: finalize ctx -> bf16 [b][1024]. grid 64, block 256 ----
__global__ __launch_bounds__(256) void k_ctx(float* __restrict__ ws) {
    int idx = blockIdx.x * 256 + threadIdx.x;     // b*1024 + k
    int b = idx >> 10, k = idx & 1023;
    float v;
    if (k < 512) {
        float s = 0.f;
        for (int c = 0; c < 64; c++) s += ws[OFF_PSUM + (b * 64 + c) * 512 + k];
        v = s * (1.0f / 4096.0f);
    } else {
        int d = k - 512;
        float m = -INFINITY;
        for (int c = 0; c < 64; c++) m = fmaxf(m, ws[OFF_PMAXP + (b * 64 + c) * 512 + d]);
        v = m;
    }
    ((unsigned short*)(ws + OFF_CTXB))[idx] = f2bf(v);
}

// ---- K2: P via MFMA: A=ctx, B=W rows -> C[b][r]. grid 512, block 256 ----
__global__ __launch_bounds__(256) void k_protos(const float* __restrict__ Wc, const float* __restrict__ pb,
                                                const float* __restrict__ bc, float* __restrict__ ws) {
    int t = threadIdx.x;
    int wave = blockIdx.x * 4 + (t >> 6);   // 0..2047 tiles of 16 W-rows
    int l = t & 63;
    int r0 = wave * 16;
    int row = r0 + (l & 15);                // this lane's W-row (B-frag col)
    int kg = l >> 4;
    const float4* W4 = (const float4*)Wc;                  // row stride 256 float4
    const short8* CB8 = (const short8*)(ws + OFF_CTXB);    // [16][128] short8 units
    f32x4 acc = (f32x4){0.f, 0.f, 0.f, 0.f};
    int wb = row * 256 + kg * 2;            // float4 idx: k = kg*8
    int cbase = (l & 15) * 128 + kg;        // A-frag: lane&15 = batch row
#pragma unroll 4
    for (int kc = 0; kc < 32; kc++) {
        float4 xa = W4[wb + kc * 8];
        float4 xb = W4[wb + kc * 8 + 1];
        short8 wf;
        wf[0] = (short)f2bf(xa.x); wf[1] = (short)f2bf(xa.y);
        wf[2] = (short)f2bf(xa.z); wf[3] = (short)f2bf(xa.w);
        wf[4] = (short)f2bf(xb.x); wf[5] = (short)f2bf(xb.y);
        wf[6] = (short)f2bf(xb.z); wf[7] = (short)f2bf(xb.w);
        short8 cf = CB8[cbase + kc * 4];
        acc = __builtin_amdgcn_mfma_f32_16x16x32_bf16(cf, wf, acc, 0, 0, 0);  // A=ctx, B=W
    }
    int r = r0 + (l & 15);
    float add = pb[r] + bc[r];
#pragma unroll
    for (int i = 0; i < 4; i++) {
        int bb = kg * 4 + i;
        ws[OFF_P + bb * MD + r] = acc[i] + add;   // 16 lanes -> 64B contiguous
    }
}

// ---- K3: Q'[b] = P[b] @ W_pre / 64 (bf16 out), fp32 math, LDS-staged P. ----
__global__ __launch_bounds__(256) void k_q(const float* __restrict__ Wp, float* __restrict__ ws) {
    __shared__ float4 lds4[512];            // P rows m0..m0+3
    int bx = blockIdx.x;
    int b = bx >> 5, mg = (bx >> 1) & 15, ch = bx & 1;
    int m0 = mg * 4, t = threadIdx.x;
    const float4* P4 = (const float4*)(ws + OFF_P + b * MD + m0 * 512);
    lds4[t] = P4[t];
    lds4[t + 256] = P4[t + 256];
    __syncthreads();
    int col = ch * 256 + t;
    const float* W = Wp + col;
    float acc0 = 0.f, acc1 = 0.f, acc2 = 0.f, acc3 = 0.f;
#pragma unroll 4
    for (int j4 = 0; j4 < 128; j4++) {
        float4 p0 = lds4[j4];
        float4 p1 = lds4[128 + j4];
        float4 p2 = lds4[256 + j4];
        float4 p3 = lds4[384 + j4];
        float w0 = W[(4 * j4 + 0) * 512];
        float w1 = W[(4 * j4 + 1) * 512];
        float w2 = W[(4 * j4 + 2) * 512];
        float w3 = W[(4 * j4 + 3) * 512];
        acc0 += p0.x * w0 + p0.y * w1 + p0.z * w2 + p0.w * w3;
        acc1 += p1.x * w0 + p1.y * w1 + p1.z * w2 + p1.w * w3;
        acc2 += p2.x * w0 + p2.y * w1 + p2.z * w2 + p2.w * w3;
        acc3 += p3.x * w0 + p3.y * w1 + p3.z * w2 + p3.w * w3;
    }
    unsigned short* Qb = (unsigned short*)(ws + OFF_QB);
    int qb = (b * 64 + m0) * 512 + col;
    Qb[qb]        = f2bf(acc0 * (1.0f / 64.0f));
    Qb[qb + 512]  = f2bf(acc1 * (1.0f / 64.0f));
    Qb[qb + 1024] = f2bf(acc2 * (1.0f / 64.0f));
    Qb[qb + 1536] = f2bf(acc3 * (1.0f / 64.0f));
}

// ---- K3b: c'[b][m] = (P[b][m] . b_pre)/64. wave per (b,m). grid 256, block 256 ----
__global__ __launch_bounds__(256) void k_cb(const float* __restrict__ bpre, float* __restrict__ ws) {
    int t = threadIdx.x;
    int w = blockIdx.x * 4 + (t >> 6);   // 0..1023 = b*64+m
    int l = t & 63;
    int b = w >> 6, m = w & 63;
    const float4* P4 = (const float4*)(ws + OFF_P + b * MD + m * 512);
    const float4* bp4 = (const float4*)bpre;
    float4 p0 = P4[l * 2],     q0 = bp4[l * 2];
    float4 p1 = P4[l * 2 + 1], q1 = bp4[l * 2 + 1];
    float s = p0.x * q0.x + p0.y * q0.y + p0.z * q0.z + p0.w * q0.w
            + p1.x * q1.x + p1.y * q1.y + p1.z * q1.z + p1.w * q1.w;
#pragma unroll
    for (int off = 1; off < 64; off <<= 1) s += __shfl_xor(s, off);
    if (l == 0) ws[OFF_CB + w] = s * (1.0f / 64.0f);
}

// ---- K4: logits from bf16 Xb via MFMA + per-tile softmax partials. grid 1024, block 256 ----
__global__ __launch_bounds__(256) void k_logits(float* __restrict__ ws) {
    int t = threadIdx.x;
    int W = blockIdx.x * 4 + (t >> 6);   // wave id 0..4095
    int b = W >> 8, nt = W & 255;        // batch, n-tile (16 rows)
    int l = t & 63, col = l & 15, kg = l >> 4;
    int nA = nt * 16 + col;              // A-fragment row
    const short8* Xb8 = (const short8*)(ws + OFF_XB);
    const short8* Qb8 = (const short8*)(ws + OFF_QB);
    f32x4 acc[4];
#pragma unroll
    for (int mt = 0; mt < 4; mt++) acc[mt] = (f32x4){0.f, 0.f, 0.f, 0.f};

    int xbase8 = (b * N_ + nA) * 64 + kg;   // short8 units per row = 64
    int qbase8 = b * 4096 + col * 64 + kg;  // (b*64+m)*64, m = mt*16+col
#pragma unroll 4
    for (int kc = 0; kc < 16; kc++) {
        short8 af = Xb8[xbase8 + kc * 4];
#pragma unroll
        for (int mt = 0; mt < 4; mt++) {
            short8 bfr = Qb8[qbase8 + mt * 1024 + kc * 4];
            acc[mt] = __builtin_amdgcn_mfma_f32_16x16x32_bf16(af, bfr, acc[mt], 0, 0, 0);
        }
    }
    const float* cb = ws + OFF_CB + b * 64;
    float* LG = ws + OFF_LOGITS + b * (N_ * 64) + nt * 16 * 64;
#pragma unroll
    for (int mt = 0; mt < 4; mt++) {
        int m = mt * 16 + col;
        float c = cb[m];
        float v0 = acc[mt][0] + c, v1 = acc[mt][1] + c;
        float v2 = acc[mt][2] + c, v3 = acc[mt][3] + c;
        int nr = kg * 4;
        LG[(nr + 0) * 64 + m] = v0;
        LG[(nr + 1) * 64 + m] = v1;
        LG[(nr + 2) * 64 + m] = v2;
        LG[(nr + 3) * 64 + m] = v3;
        float mx = fmaxf(fmaxf(v0, v1), fmaxf(v2, v3));
        mx = fmaxf(mx, __shfl_xor(mx, 16));
        mx = fmaxf(mx, __shfl_xor(mx, 32));
        float s = expf(v0 - mx) + expf(v1 - mx) + expf(v2 - mx) + expf(v3 - mx);
        s += __shfl_xor(s, 16);
        s += __shfl_xor(s, 32);
        if (kg == 0) {
            ws[OFF_TPMAX + (b * 64 + m) * 256 + nt] = mx;
            ws[OFF_TPSUM + (b * 64 + m) * 256 + nt] = s;
        }
    }
}

// ---- K5: combine partials -> gmax, 1/denom. wave per (b,m). grid 256, block 256 ----
__global__ __launch_bounds__(256) void k_combine(float* __restrict__ ws) {
    int t = threadIdx.x;
    int w = blockIdx.x * 4 + (t >> 6);   // 0..1023 = b*64+m
    int l = t & 63;
    float4 a  = ((const float4*)(ws + OFF_TPMAX + w * 256))[l];
    float4 s4 = ((const float4*)(ws + OFF_TPSUM + w * 256))[l];
    float g = fmaxf(fmaxf(a.x, a.y), fmaxf(a.z, a.w));
    float s = s4.x * expf(a.x - g) + s4.y * expf(a.y - g)
            + s4.z * expf(a.z - g) + s4.w * expf(a.w - g);
#pragma unroll
    for (int off = 1; off < 64; off <<= 1) {
        float og = __shfl_xor(g, off);
        float os = __shfl_xor(s, off);
        float ng = fmaxf(g, og);
        s = s * expf(g - ng) + os * expf(og - ng);
        g = ng;
    }
    if (l == 0) { ws[OFF_GMAX + w] = g; ws[OFF_GINV + w] = 1.0f / s; }
}

// ---- K6: out = exp(l - gmax) * ginv. grid 4096, block 256 ----
__global__ __launch_bounds__(256) void k_final(const float* __restrict__ ws, float* __restrict__ out) {
    int idx = blockIdx.x * 256 + threadIdx.x;   // float4 index
    int flat = idx * 4;
    int b = flat >> 18;                         // / (4096*64)
    int m0 = flat & 63;                         // multiple of 4
    float4 l4 = ((const float4*)(ws + OFF_LOGITS))[idx];
    int bm = b * 64 + m0;
    float4 g4 = *(const float4*)(ws + OFF_GMAX + bm);
    float4 i4 = *(const float4*)(ws + OFF_GINV + bm);
    float4 o;
    o.x = expf(l4.x - g4.x) * i4.x;
    o.y = expf(l4.y - g4.y) * i4.y;
    o.z = expf(l4.z - g4.z) * i4.z;
    o.w = expf(l4.w - g4.w) * i4.w;
    ((float4*)out)[idx] = o;
}

extern "C" void kernel_launch(void* const* d_in, const int* in_sizes, int n_in,
                              void* d_out, int out_size, void* d_ws, size_t ws_size,
                              hipStream_t stream) {
    const float* X  = (const float*)d_in[0];
    const float* pb = (const float*)d_in[1];
    const float* Wc = (const float*)d_in[2];
    const float* bc = (const float*)d_in[3];
    const float* Wp = (const float*)d_in[4];
    const float* bp = (const float*)d_in[5];
    float* ws  = (float*)d_ws;
    float* out = (float*)d_out;

    k_pool<<<512, 256, 0, stream>>>(X, ws);
    k_ctx<<<64, 256, 0, stream>>>(ws);
    k_protos<<<512, 256, 0, stream>>>(Wc, pb, bc, ws);
    k_q<<<512, 256, 0, stream>>>(Wp, ws);
    k_cb<<<256, 256, 0, stream>>>(bp, ws);
    k_logits<<<1024, 256, 0, stream>>>(ws);
    k_combine<<<256, 256, 0, stream>>>(ws);
    k_final<<<4096, 256, 0, stream>>>(ws, out);
}

// Round 7
// 165.690 us; speedup vs baseline: 1.0529x; 1.0529x over previous
//
#include <hip/hip_runtime.h>
#include <math.h>

#define B_ 16
#define N_ 4096
#define D_ 512
#define M_ 64
#define MD 32768   // M_*D_

typedef __attribute__((ext_vector_type(4))) float f32x4;
typedef __attribute__((ext_vector_type(8))) short short8;

// ---- workspace layout (float offsets) ----
#define OFF_PSUM   0          // [16][128][512] pooling sum partials (1048576)
#define OFF_PMAXP  1048576    // [16][128][512] pooling max partials (1048576)
#define OFF_CTXB   2097152    // bf16 [16][1024] ctx (8192 floats)
#define OFF_P      2105344    // fp32 P[b][m*512+d] natural (524288)
#define OFF_CB     2629632    // [16][64]
#define OFF_GMAX   2630656    // [16][64]
#define OFF_GINV   2631680    // [16][64]
#define OFF_TPMAX  2632704    // [1024][256] (262144)
#define OFF_TPSUM  2894848    // [1024][256] (262144)
#define OFF_QB     3156992    // bf16 [16][64][512] (262144 floats)
#define OFF_LGB    3419136    // bf16 [16][4096][64] (2097152 floats)
// total = 5516288 floats = 22.1 MB

__device__ __forceinline__ unsigned short f2bf(float f) {
    unsigned int u = __float_as_uint(f);
    u += 0x7fffu + ((u >> 16) & 1u);   // round-to-nearest-even
    return (unsigned short)(u >> 16);
}

// ---- K1: pooling partials. grid 1024 (b*64+nc), block 256 ----
// thread: cols 4c..4c+3 (c=t&127), rows nc*64 + 2*i + p (p=t>>7), i<32
__global__ __launch_bounds__(256) void k_pool(const float* __restrict__ X, float* __restrict__ ws) {
    int b = blockIdx.x >> 6, nc = blockIdx.x & 63, t = threadIdx.x;
    int c = t & 127, p = t >> 7;
    const float4* X4 = (const float4*)X;
    float4 s = make_float4(0.f, 0.f, 0.f, 0.f);
    float4 mx = make_float4(-INFINITY, -INFINITY, -INFINITY, -INFINITY);
    int rowbase = b * N_ + nc * 64 + p;
    for (int i = 0; i < 32; i++) {
        int n = rowbase + 2 * i;
        float4 v = X4[n * 128 + c];
        s.x += v.x; s.y += v.y; s.z += v.z; s.w += v.w;
        mx.x = fmaxf(mx.x, v.x); mx.y = fmaxf(mx.y, v.y);
        mx.z = fmaxf(mx.z, v.z); mx.w = fmaxf(mx.w, v.w);
    }
    int slot = (b * 128 + nc * 2 + p) * 128 + c;   // float4 units
    ((float4*)(ws + OFF_PSUM))[slot] = s;
    ((float4*)(ws + OFF_PMAXP))[slot] = mx;
}

// ---- K1b: finalize ctx -> bf16 [b][1024]. grid 64, block 256 ----
__global__ __launch_bounds__(256) void k_ctx(float* __restrict__ ws) {
    int idx = blockIdx.x * 256 + threadIdx.x;     // b*1024 + k
    int b = idx >> 10, k = idx & 1023;
    float v;
    if (k < 512) {
        float s = 0.f;
        for (int c = 0; c < 128; c++) s += ws[OFF_PSUM + (b * 128 + c) * 512 + k];
        v = s * (1.0f / 4096.0f);
    } else {
        int d = k - 512;
        float m = -INFINITY;
        for (int c = 0; c < 128; c++) m = fmaxf(m, ws[OFF_PMAXP + (b * 128 + c) * 512 + d]);
        v = m;
    }
    ((unsigned short*)(ws + OFF_CTXB))[idx] = f2bf(v);
}

// ---- K2: P via MFMA: A=ctx, B=W rows -> C[b][r]. grid 512, block 256 ----
__global__ __launch_bounds__(256) void k_protos(const float* __restrict__ Wc, const float* __restrict__ pb,
                                                const float* __restrict__ bc, float* __restrict__ ws) {
    int t = threadIdx.x;
    int wave = blockIdx.x * 4 + (t >> 6);   // 0..2047 tiles of 16 W-rows
    int l = t & 63;
    int r0 = wave * 16;
    int row = r0 + (l & 15);                // this lane's W-row (B-frag col)
    int kg = l >> 4;
    const float4* W4 = (const float4*)Wc;                  // row stride 256 float4
    const short8* CB8 = (const short8*)(ws + OFF_CTXB);    // [16][128] short8 units
    f32x4 acc = (f32x4){0.f, 0.f, 0.f, 0.f};
    int wb = row * 256 + kg * 2;            // float4 idx: k = kg*8
    int cbase = (l & 15) * 128 + kg;        // A-frag: lane&15 = batch row
#pragma unroll 4
    for (int kc = 0; kc < 32; kc++) {
        float4 xa = W4[wb + kc * 8];
        float4 xb = W4[wb + kc * 8 + 1];
        short8 wf;
        wf[0] = (short)f2bf(xa.x); wf[1] = (short)f2bf(xa.y);
        wf[2] = (short)f2bf(xa.z); wf[3] = (short)f2bf(xa.w);
        wf[4] = (short)f2bf(xb.x); wf[5] = (short)f2bf(xb.y);
        wf[6] = (short)f2bf(xb.z); wf[7] = (short)f2bf(xb.w);
        short8 cf = CB8[cbase + kc * 4];
        acc = __builtin_amdgcn_mfma_f32_16x16x32_bf16(cf, wf, acc, 0, 0, 0);  // A=ctx, B=W
    }
    int r = r0 + (l & 15);
    float add = pb[r] + bc[r];
#pragma unroll
    for (int i = 0; i < 4; i++) {
        int bb = kg * 4 + i;
        ws[OFF_P + bb * MD + r] = acc[i] + add;   // 16 lanes -> 64B contiguous
    }
}

// ---- K3: Q'[b] = P[b] @ W_pre / 64 (bf16 out) + c' fold. grid 512, block 256 ----
__global__ __launch_bounds__(256) void k_q(const float* __restrict__ Wp, const float* __restrict__ bpre,
                                           float* __restrict__ ws) {
    __shared__ float4 lds4[512];            // P rows m0..m0+3
    int bx = blockIdx.x;
    int b = bx >> 5, mg = (bx >> 1) & 15, ch = bx & 1;
    int m0 = mg * 4, t = threadIdx.x;
    const float4* P4 = (const float4*)(ws + OFF_P + b * MD + m0 * 512);
    lds4[t] = P4[t];
    lds4[t + 256] = P4[t + 256];
    __syncthreads();
    if (ch == 0) {                          // fold c'[b][m0..m0+3]
        int w = t >> 6, l = t & 63;
        const float4* bp4 = (const float4*)bpre;
        float4 p0 = lds4[w * 128 + l * 2],     q0 = bp4[l * 2];
        float4 p1 = lds4[w * 128 + l * 2 + 1], q1 = bp4[l * 2 + 1];
        float s = p0.x * q0.x + p0.y * q0.y + p0.z * q0.z + p0.w * q0.w
                + p1.x * q1.x + p1.y * q1.y + p1.z * q1.z + p1.w * q1.w;
#pragma unroll
        for (int off = 1; off < 64; off <<= 1) s += __shfl_xor(s, off);
        if (l == 0) ws[OFF_CB + b * 64 + m0 + w] = s * (1.0f / 64.0f);
    }
    int col = ch * 256 + t;
    const float* W = Wp + col;
    float acc0 = 0.f, acc1 = 0.f, acc2 = 0.f, acc3 = 0.f;
#pragma unroll 4
    for (int j4 = 0; j4 < 128; j4++) {
        float4 p0 = lds4[j4];
        float4 p1 = lds4[128 + j4];
        float4 p2 = lds4[256 + j4];
        float4 p3 = lds4[384 + j4];
        float w0 = W[(4 * j4 + 0) * 512];
        float w1 = W[(4 * j4 + 1) * 512];
        float w2 = W[(4 * j4 + 2) * 512];
        float w3 = W[(4 * j4 + 3) * 512];
        acc0 += p0.x * w0 + p0.y * w1 + p0.z * w2 + p0.w * w3;
        acc1 += p1.x * w0 + p1.y * w1 + p1.z * w2 + p1.w * w3;
        acc2 += p2.x * w0 + p2.y * w1 + p2.z * w2 + p2.w * w3;
        acc3 += p3.x * w0 + p3.y * w1 + p3.z * w2 + p3.w * w3;
    }
    unsigned short* Qb = (unsigned short*)(ws + OFF_QB);
    int qb = (b * 64 + m0) * 512 + col;
    Qb[qb]        = f2bf(acc0 * (1.0f / 64.0f));
    Qb[qb + 512]  = f2bf(acc1 * (1.0f / 64.0f));
    Qb[qb + 1024] = f2bf(acc2 * (1.0f / 64.0f));
    Qb[qb + 1536] = f2bf(acc3 * (1.0f / 64.0f));
}

// ---- K4: logits = X.Q'^T + c' via bf16 MFMA; LG stored bf16. grid 1024, block 256 ----
__global__ __launch_bounds__(256) void k_logits(const float* __restrict__ X, float* __restrict__ ws) {
    int t = threadIdx.x;
    int W = blockIdx.x * 4 + (t >> 6);   // wave id 0..4095
    int b = W >> 8, nt = W & 255;        // batch, n-tile (16 rows)
    int l = t & 63, col = l & 15, kg = l >> 4;
    int nA = nt * 16 + col;              // A-fragment row
    const float4* X4 = (const float4*)X;
    const short8* Qb8 = (const short8*)(ws + OFF_QB);
    f32x4 acc[4];
#pragma unroll
    for (int mt = 0; mt < 4; mt++) acc[mt] = (f32x4){0.f, 0.f, 0.f, 0.f};

    int xbase4 = ((b * N_ + nA) * D_) >> 2;
    int qbase8 = b * 4096 + col * 64 + kg;  // (b*64+m)*64 short8-units, m = mt*16+col
    for (int kc = 0; kc < 16; kc++) {
        float4 xa = X4[xbase4 + kc * 8 + kg * 2];
        float4 xb = X4[xbase4 + kc * 8 + kg * 2 + 1];
        short8 af;
        af[0] = (short)f2bf(xa.x); af[1] = (short)f2bf(xa.y);
        af[2] = (short)f2bf(xa.z); af[3] = (short)f2bf(xa.w);
        af[4] = (short)f2bf(xb.x); af[5] = (short)f2bf(xb.y);
        af[6] = (short)f2bf(xb.z); af[7] = (short)f2bf(xb.w);
#pragma unroll
        for (int mt = 0; mt < 4; mt++) {
            short8 bfr = Qb8[qbase8 + mt * 1024 + kc * 4];
            acc[mt] = __builtin_amdgcn_mfma_f32_16x16x32_bf16(af, bfr, acc[mt], 0, 0, 0);
        }
    }
    const float* cb = ws + OFF_CB + b * 64;
    unsigned short* LGB = (unsigned short*)(ws + OFF_LGB) + b * (N_ * 64) + nt * 16 * 64;
#pragma unroll
    for (int mt = 0; mt < 4; mt++) {
        int m = mt * 16 + col;
        float c = cb[m];
        float v0 = acc[mt][0] + c, v1 = acc[mt][1] + c;
        float v2 = acc[mt][2] + c, v3 = acc[mt][3] + c;
        int nr = kg * 4;
        LGB[(nr + 0) * 64 + m] = f2bf(v0);
        LGB[(nr + 1) * 64 + m] = f2bf(v1);
        LGB[(nr + 2) * 64 + m] = f2bf(v2);
        LGB[(nr + 3) * 64 + m] = f2bf(v3);
        float mx = fmaxf(fmaxf(v0, v1), fmaxf(v2, v3));
        mx = fmaxf(mx, __shfl_xor(mx, 16));
        mx = fmaxf(mx, __shfl_xor(mx, 32));
        float s = expf(v0 - mx) + expf(v1 - mx) + expf(v2 - mx) + expf(v3 - mx);
        s += __shfl_xor(s, 16);
        s += __shfl_xor(s, 32);
        if (kg == 0) {
            ws[OFF_TPMAX + (b * 64 + m) * 256 + nt] = mx;
            ws[OFF_TPSUM + (b * 64 + m) * 256 + nt] = s;
        }
    }
}

// ---- K5: combine partials -> gmax, 1/denom. wave per (b,m). grid 256, block 256 ----
__global__ __launch_bounds__(256) void k_combine(float* __restrict__ ws) {
    int t = threadIdx.x;
    int w = blockIdx.x * 4 + (t >> 6);   // 0..1023 = b*64+m
    int l = t & 63;
    float4 a  = ((const float4*)(ws + OFF_TPMAX + w * 256))[l];
    float4 s4 = ((const float4*)(ws + OFF_TPSUM + w * 256))[l];
    float g = fmaxf(fmaxf(a.x, a.y), fmaxf(a.z, a.w));
    float s = s4.x * expf(a.x - g) + s4.y * expf(a.y - g)
            + s4.z * expf(a.z - g) + s4.w * expf(a.w - g);
#pragma unroll
    for (int off = 1; off < 64; off <<= 1) {
        float og = __shfl_xor(g, off);
        float os = __shfl_xor(s, off);
        float ng = fmaxf(g, og);
        s = s * expf(g - ng) + os * expf(og - ng);
        g = ng;
    }
    if (l == 0) { ws[OFF_GMAX + w] = g; ws[OFF_GINV + w] = 1.0f / s; }
}

// ---- K6: out = exp(bf16(l) - gmax) * ginv. grid 2048, block 256 (8 elems/thread) ----
__global__ __launch_bounds__(256) void k_final(const float* __restrict__ ws, float* __restrict__ out) {
    int idx = blockIdx.x * 256 + threadIdx.x;   // uint4 (8 bf16) index
    int flat = idx * 8;
    int b = flat >> 18;                         // / (4096*64)
    int m0 = flat & 63;                         // multiple of 8
    uint4 lg = ((const uint4*)((const unsigned short*)(ws + OFF_LGB)))[idx];
    int bm = b * 64 + m0;
    float4 ga = *(const float4*)(ws + OFF_GMAX + bm);
    float4 gb = *(const float4*)(ws + OFF_GMAX + bm + 4);
    float4 ia = *(const float4*)(ws + OFF_GINV + bm);
    float4 ib = *(const float4*)(ws + OFF_GINV + bm + 4);
    float4 o0, o1;
    o0.x = expf(__uint_as_float(lg.x << 16)         - ga.x) * ia.x;
    o0.y = expf(__uint_as_float(lg.x & 0xffff0000u) - ga.y) * ia.y;
    o0.z = expf(__uint_as_float(lg.y << 16)         - ga.z) * ia.z;
    o0.w = expf(__uint_as_float(lg.y & 0xffff0000u) - ga.w) * ia.w;
    o1.x = expf(__uint_as_float(lg.z << 16)         - gb.x) * ib.x;
    o1.y = expf(__uint_as_float(lg.z & 0xffff0000u) - gb.y) * ib.y;
    o1.z = expf(__uint_as_float(lg.w << 16)         - gb.z) * ib.z;
    o1.w = expf(__uint_as_float(lg.w & 0xffff0000u) - gb.w) * ib.w;
    ((float4*)out)[idx * 2]     = o0;
    ((float4*)out)[idx * 2 + 1] = o1;
}

extern "C" void kernel_launch(void* const* d_in, const int* in_sizes, int n_in,
                              void* d_out, int out_size, void* d_ws, size_t ws_size,
                              hipStream_t stream) {
    const float* X  = (const float*)d_in[0];
    const float* pb = (const float*)d_in[1];
    const float* Wc = (const float*)d_in[2];
    const float* bc = (const float*)d_in[3];
    const float* Wp = (const float*)d_in[4];
    const float* bp = (const float*)d_in[5];
    float* ws  = (float*)d_ws;
    float* out = (float*)d_out;

    k_pool<<<1024, 256, 0, stream>>>(X, ws);
    k_ctx<<<64, 256, 0, stream>>>(ws);
    k_protos<<<512, 256, 0, stream>>>(Wc, pb, bc, ws);
    k_q<<<512, 256, 0, stream>>>(Wp, bp, ws);
    k_logits<<<1024, 256, 0, stream>>>(X, ws);
    k_combine<<<256, 256, 0, stream>>>(ws);
    k_final<<<2048, 256, 0, stream>>>(ws, out);
}

// Round 8
// 163.072 us; speedup vs baseline: 1.0698x; 1.0161x over previous
//
#include <hip/hip_runtime.h>
#include <math.h>

#define B_ 16
#define N_ 4096
#define D_ 512
#define M_ 64
#define MD 32768   // M_*D_

typedef __attribute__((ext_vector_type(4))) float f32x4;
typedef __attribute__((ext_vector_type(8))) short short8;

// ---- workspace layout (float offsets) ----
#define OFF_PSUM   0          // [16][128][512] pooling sum partials (1048576)
#define OFF_PMAXP  1048576    // [16][128][512] pooling max partials (1048576)
#define OFF_CTXB   2097152    // bf16 [16][1024] ctx (8192 floats)
#define OFF_P      2105344    // fp32 P[b][m*512+d] natural (524288)
#define OFF_CB     2629632    // [16][64]
#define OFF_GMAX   2630656    // [16][64]
#define OFF_GINV   2631680    // [16][64]
#define OFF_TPMAX  2632704    // [1024][256] (262144)
#define OFF_TPSUM  2894848    // [1024][256] (262144)
#define OFF_QB     3156992    // bf16 [16][64][512] (262144 floats)
#define OFF_LGB    3419136    // bf16 [16][4096][64] (2097152 floats)
// total = 5516288 floats = 22.1 MB

__device__ __forceinline__ unsigned short f2bf(float f) {
    unsigned int u = __float_as_uint(f);
    u += 0x7fffu + ((u >> 16) & 1u);   // round-to-nearest-even
    return (unsigned short)(u >> 16);
}

// ---- K1: pooling partials. grid 1024 (b*64+nc), block 256 ----
__global__ __launch_bounds__(256) void k_pool(const float* __restrict__ X, float* __restrict__ ws) {
    int b = blockIdx.x >> 6, nc = blockIdx.x & 63, t = threadIdx.x;
    int c = t & 127, p = t >> 7;
    const float4* X4 = (const float4*)X;
    float4 s = make_float4(0.f, 0.f, 0.f, 0.f);
    float4 mx = make_float4(-INFINITY, -INFINITY, -INFINITY, -INFINITY);
    int rowbase = b * N_ + nc * 64 + p;
#pragma unroll 8
    for (int i = 0; i < 32; i++) {
        int n = rowbase + 2 * i;
        float4 v = X4[n * 128 + c];
        s.x += v.x; s.y += v.y; s.z += v.z; s.w += v.w;
        mx.x = fmaxf(mx.x, v.x); mx.y = fmaxf(mx.y, v.y);
        mx.z = fmaxf(mx.z, v.z); mx.w = fmaxf(mx.w, v.w);
    }
    int slot = (b * 128 + nc * 2 + p) * 128 + c;   // float4 units
    ((float4*)(ws + OFF_PSUM))[slot] = s;
    ((float4*)(ws + OFF_PMAXP))[slot] = mx;
}

// ---- K1b: finalize ctx -> bf16 [b][1024]. grid 16, block 256, float4/thread ----
__global__ __launch_bounds__(256) void k_ctx(float* __restrict__ ws) {
    int idx = blockIdx.x * 256 + threadIdx.x;     // 0..4095 = b*256 + k4
    int b = idx >> 8, k4 = idx & 255;
    const float4* PS4 = (const float4*)(ws + OFF_PSUM);
    const float4* PM4 = (const float4*)(ws + OFF_PMAXP);
    float4 r;
    if (k4 < 128) {
        float4 s = make_float4(0.f, 0.f, 0.f, 0.f);
#pragma unroll 8
        for (int c = 0; c < 128; c++) {
            float4 v = PS4[(b * 128 + c) * 128 + k4];
            s.x += v.x; s.y += v.y; s.z += v.z; s.w += v.w;
        }
        r.x = s.x * (1.0f / 4096.0f); r.y = s.y * (1.0f / 4096.0f);
        r.z = s.z * (1.0f / 4096.0f); r.w = s.w * (1.0f / 4096.0f);
    } else {
        int d4 = k4 - 128;
        float4 m = make_float4(-INFINITY, -INFINITY, -INFINITY, -INFINITY);
#pragma unroll 8
        for (int c = 0; c < 128; c++) {
            float4 v = PM4[(b * 128 + c) * 128 + d4];
            m.x = fmaxf(m.x, v.x); m.y = fmaxf(m.y, v.y);
            m.z = fmaxf(m.z, v.z); m.w = fmaxf(m.w, v.w);
        }
        r = m;
    }
    ushort4 o;
    o.x = f2bf(r.x); o.y = f2bf(r.y); o.z = f2bf(r.z); o.w = f2bf(r.w);
    ((ushort4*)(ws + OFF_CTXB))[idx] = o;
}

// ---- K2: P via MFMA: A=ctx, B=W rows -> C[b][r]. grid 512, block 256 ----
__global__ __launch_bounds__(256) void k_protos(const float* __restrict__ Wc, const float* __restrict__ pb,
                                                const float* __restrict__ bc, float* __restrict__ ws) {
    int t = threadIdx.x;
    int wave = blockIdx.x * 4 + (t >> 6);   // 0..2047 tiles of 16 W-rows
    int l = t & 63;
    int r0 = wave * 16;
    int row = r0 + (l & 15);                // this lane's W-row (B-frag col)
    int kg = l >> 4;
    const float4* W4 = (const float4*)Wc;                  // row stride 256 float4
    const short8* CB8 = (const short8*)(ws + OFF_CTXB);    // [16][128] short8 units
    f32x4 acc = (f32x4){0.f, 0.f, 0.f, 0.f};
    int wb = row * 256 + kg * 2;            // float4 idx: k = kg*8
    int cbase = (l & 15) * 128 + kg;        // A-frag: lane&15 = batch row
#pragma unroll 8
    for (int kc = 0; kc < 32; kc++) {
        float4 xa = W4[wb + kc * 8];
        float4 xb = W4[wb + kc * 8 + 1];
        short8 wf;
        wf[0] = (short)f2bf(xa.x); wf[1] = (short)f2bf(xa.y);
        wf[2] = (short)f2bf(xa.z); wf[3] = (short)f2bf(xa.w);
        wf[4] = (short)f2bf(xb.x); wf[5] = (short)f2bf(xb.y);
        wf[6] = (short)f2bf(xb.z); wf[7] = (short)f2bf(xb.w);
        short8 cf = CB8[cbase + kc * 4];
        acc = __builtin_amdgcn_mfma_f32_16x16x32_bf16(cf, wf, acc, 0, 0, 0);  // A=ctx, B=W
    }
    int r = r0 + (l & 15);
    float add = pb[r] + bc[r];
#pragma unroll
    for (int i = 0; i < 4; i++) {
        int bb = kg * 4 + i;
        ws[OFF_P + bb * MD + r] = acc[i] + add;   // 16 lanes -> 64B contiguous
    }
}

// ---- K3: Q'[b] = P[b] @ W_pre / 64 (bf16 out) + c' fold. grid 512, block 256 ----
__global__ __launch_bounds__(256) void k_q(const float* __restrict__ Wp, const float* __restrict__ bpre,
                                           float* __restrict__ ws) {
    __shared__ float4 lds4[512];            // P rows m0..m0+3
    int bx = blockIdx.x;
    int b = bx >> 5, mg = (bx >> 1) & 15, ch = bx & 1;
    int m0 = mg * 4, t = threadIdx.x;
    const float4* P4 = (const float4*)(ws + OFF_P + b * MD + m0 * 512);
    lds4[t] = P4[t];
    lds4[t + 256] = P4[t + 256];
    __syncthreads();
    if (ch == 0) {                          // fold c'[b][m0..m0+3]
        int w = t >> 6, l = t & 63;
        const float4* bp4 = (const float4*)bpre;
        float4 p0 = lds4[w * 128 + l * 2],     q0 = bp4[l * 2];
        float4 p1 = lds4[w * 128 + l * 2 + 1], q1 = bp4[l * 2 + 1];
        float s = p0.x * q0.x + p0.y * q0.y + p0.z * q0.z + p0.w * q0.w
                + p1.x * q1.x + p1.y * q1.y + p1.z * q1.z + p1.w * q1.w;
#pragma unroll
        for (int off = 1; off < 64; off <<= 1) s += __shfl_xor(s, off);
        if (l == 0) ws[OFF_CB + b * 64 + m0 + w] = s * (1.0f / 64.0f);
    }
    int col = ch * 256 + t;
    const float* W = Wp + col;
    float acc0 = 0.f, acc1 = 0.f, acc2 = 0.f, acc3 = 0.f;
#pragma unroll 8
    for (int j4 = 0; j4 < 128; j4++) {
        float4 p0 = lds4[j4];
        float4 p1 = lds4[128 + j4];
        float4 p2 = lds4[256 + j4];
        float4 p3 = lds4[384 + j4];
        float w0 = W[(4 * j4 + 0) * 512];
        float w1 = W[(4 * j4 + 1) * 512];
        float w2 = W[(4 * j4 + 2) * 512];
        float w3 = W[(4 * j4 + 3) * 512];
        acc0 += p0.x * w0 + p0.y * w1 + p0.z * w2 + p0.w * w3;
        acc1 += p1.x * w0 + p1.y * w1 + p1.z * w2 + p1.w * w3;
        acc2 += p2.x * w0 + p2.y * w1 + p2.z * w2 + p2.w * w3;
        acc3 += p3.x * w0 + p3.y * w1 + p3.z * w2 + p3.w * w3;
    }
    unsigned short* Qb = (unsigned short*)(ws + OFF_QB);
    int qb = (b * 64 + m0) * 512 + col;
    Qb[qb]        = f2bf(acc0 * (1.0f / 64.0f));
    Qb[qb + 512]  = f2bf(acc1 * (1.0f / 64.0f));
    Qb[qb + 1024] = f2bf(acc2 * (1.0f / 64.0f));
    Qb[qb + 1536] = f2bf(acc3 * (1.0f / 64.0f));
}

// ---- K4: logits = X.Q'^T + c' via bf16 MFMA; LG stored bf16. grid 1024, block 256 ----
__global__ __launch_bounds__(256) void k_logits(const float* __restrict__ X, float* __restrict__ ws) {
    int t = threadIdx.x;
    int W = blockIdx.x * 4 + (t >> 6);   // wave id 0..4095
    int b = W >> 8, nt = W & 255;        // batch, n-tile (16 rows)
    int l = t & 63, col = l & 15, kg = l >> 4;
    int nA = nt * 16 + col;              // A-fragment row
    const float4* X4 = (const float4*)X;
    const short8* Qb8 = (const short8*)(ws + OFF_QB);
    f32x4 acc[4];
#pragma unroll
    for (int mt = 0; mt < 4; mt++) acc[mt] = (f32x4){0.f, 0.f, 0.f, 0.f};

    int xbase4 = ((b * N_ + nA) * D_) >> 2;
    int qbase8 = b * 4096 + col * 64 + kg;  // (b*64+m)*64 short8-units, m = mt*16+col
#pragma unroll 2
    for (int kc = 0; kc < 16; kc++) {
        float4 xa = X4[xbase4 + kc * 8 + kg * 2];
        float4 xb = X4[xbase4 + kc * 8 + kg * 2 + 1];
        short8 af;
        af[0] = (short)f2bf(xa.x); af[1] = (short)f2bf(xa.y);
        af[2] = (short)f2bf(xa.z); af[3] = (short)f2bf(xa.w);
        af[4] = (short)f2bf(xb.x); af[5] = (short)f2bf(xb.y);
        af[6] = (short)f2bf(xb.z); af[7] = (short)f2bf(xb.w);
#pragma unroll
        for (int mt = 0; mt < 4; mt++) {
            short8 bfr = Qb8[qbase8 + mt * 1024 + kc * 4];
            acc[mt] = __builtin_amdgcn_mfma_f32_16x16x32_bf16(af, bfr, acc[mt], 0, 0, 0);
        }
    }
    const float* cb = ws + OFF_CB + b * 64;
    unsigned short* LGB = (unsigned short*)(ws + OFF_LGB) + b * (N_ * 64) + nt * 16 * 64;
#pragma unroll
    for (int mt = 0; mt < 4; mt++) {
        int m = mt * 16 + col;
        float c = cb[m];
        float v0 = acc[mt][0] + c, v1 = acc[mt][1] + c;
        float v2 = acc[mt][2] + c, v3 = acc[mt][3] + c;
        int nr = kg * 4;
        LGB[(nr + 0) * 64 + m] = f2bf(v0);
        LGB[(nr + 1) * 64 + m] = f2bf(v1);
        LGB[(nr + 2) * 64 + m] = f2bf(v2);
        LGB[(nr + 3) * 64 + m] = f2bf(v3);
        float mx = fmaxf(fmaxf(v0, v1), fmaxf(v2, v3));
        mx = fmaxf(mx, __shfl_xor(mx, 16));
        mx = fmaxf(mx, __shfl_xor(mx, 32));
        float s = expf(v0 - mx) + expf(v1 - mx) + expf(v2 - mx) + expf(v3 - mx);
        s += __shfl_xor(s, 16);
        s += __shfl_xor(s, 32);
        if (kg == 0) {
            ws[OFF_TPMAX + (b * 64 + m) * 256 + nt] = mx;
            ws[OFF_TPSUM + (b * 64 + m) * 256 + nt] = s;
        }
    }
}

// ---- K5: combine partials -> gmax, 1/denom. wave per (b,m). grid 256, block 256 ----
__global__ __launch_bounds__(256) void k_combine(float* __restrict__ ws) {
    int t = threadIdx.x;
    int w = blockIdx.x * 4 + (t >> 6);   // 0..1023 = b*64+m
    int l = t & 63;
    float4 a  = ((const float4*)(ws + OFF_TPMAX + w * 256))[l];
    float4 s4 = ((const float4*)(ws + OFF_TPSUM + w * 256))[l];
    float g = fmaxf(fmaxf(a.x, a.y), fmaxf(a.z, a.w));
    float s = s4.x * expf(a.x - g) + s4.y * expf(a.y - g)
            + s4.z * expf(a.z - g) + s4.w * expf(a.w - g);
#pragma unroll
    for (int off = 1; off < 64; off <<= 1) {
        float og = __shfl_xor(g, off);
        float os = __shfl_xor(s, off);
        float ng = fmaxf(g, og);
        s = s * expf(g - ng) + os * expf(og - ng);
        g = ng;
    }
    if (l == 0) { ws[OFF_GMAX + w] = g; ws[OFF_GINV + w] = 1.0f / s; }
}

// ---- K6: out = exp(bf16(l) - gmax) * ginv. grid 2048, block 256 (8 elems/thread) ----
__global__ __launch_bounds__(256) void k_final(const float* __restrict__ ws, float* __restrict__ out) {
    int idx = blockIdx.x * 256 + threadIdx.x;   // uint4 (8 bf16) index
    int flat = idx * 8;
    int b = flat >> 18;                         // / (4096*64)
    int m0 = flat & 63;                         // multiple of 8
    uint4 lg = ((const uint4*)((const unsigned short*)(ws + OFF_LGB)))[idx];
    int bm = b * 64 + m0;
    float4 ga = *(const float4*)(ws + OFF_GMAX + bm);
    float4 gb = *(const float4*)(ws + OFF_GMAX + bm + 4);
    float4 ia = *(const float4*)(ws + OFF_GINV + bm);
    float4 ib = *(const float4*)(ws + OFF_GINV + bm + 4);
    float4 o0, o1;
    o0.x = expf(__uint_as_float(lg.x << 16)         - ga.x) * ia.x;
    o0.y = expf(__uint_as_float(lg.x & 0xffff0000u) - ga.y) * ia.y;
    o0.z = expf(__uint_as_float(lg.y << 16)         - ga.z) * ia.z;
    o0.w = expf(__uint_as_float(lg.y & 0xffff0000u) - ga.w) * ia.w;
    o1.x = expf(__uint_as_float(lg.z << 16)         - gb.x) * ib.x;
    o1.y = expf(__uint_as_float(lg.z & 0xffff0000u) - gb.y) * ib.y;
    o1.z = expf(__uint_as_float(lg.w << 16)         - gb.z) * ib.z;
    o1.w = expf(__uint_as_float(lg.w & 0xffff0000u) - gb.w) * ib.w;
    ((float4*)out)[idx * 2]     = o0;
    ((float4*)out)[idx * 2 + 1] = o1;
}

extern "C" void kernel_launch(void* const* d_in, const int* in_sizes, int n_in,
                              void* d_out, int out_size, void* d_ws, size_t ws_size,
                              hipStream_t stream) {
    const float* X  = (const float*)d_in[0];
    const float* pb = (const float*)d_in[1];
    const float* Wc = (const float*)d_in[2];
    const float* bc = (const float*)d_in[3];
    const float* Wp = (const float*)d_in[4];
    const float* bp = (const float*)d_in[5];
    float* ws  = (float*)d_ws;
    float* out = (float*)d_out;

    k_pool<<<1024, 256, 0, stream>>>(X, ws);
    k_ctx<<<16, 256, 0, stream>>>(ws);
    k_protos<<<512, 256, 0, stream>>>(Wc, pb, bc, ws);
    k_q<<<512, 256, 0, stream>>>(Wp, bp, ws);
    k_logits<<<1024, 256, 0, stream>>>(X, ws);
    k_combine<<<256, 256, 0, stream>>>(ws);
    k_final<<<2048, 256, 0, stream>>>(ws, out);
}

// Round 9
// 158.465 us; speedup vs baseline: 1.1009x; 1.0291x over previous
//
#include <hip/hip_runtime.h>
#include <math.h>

#define B_ 16
#define N_ 4096
#define D_ 512
#define M_ 64
#define MD 32768   // M_*D_

typedef __attribute__((ext_vector_type(4))) float f32x4;
typedef __attribute__((ext_vector_type(8))) short short8;

// ---- workspace layout (float offsets) ----
#define OFF_PSUM   0          // [16][128][512] pooling sum partials (1048576)
#define OFF_PMAXP  1048576    // [16][128][512] pooling max partials (1048576)
#define OFF_CTXB   2097152    // bf16 [16][1024] ctx (8192 floats)
#define OFF_P      2105344    // fp32 P[b][m*512+d] natural (524288)
#define OFF_CB     2629632    // [16][64]
#define OFF_GMAX   2630656    // [16][64]
#define OFF_GINV   2631680    // [16][64]
#define OFF_TPMAX  2632704    // [1024][256] (262144)
#define OFF_TPSUM  2894848    // [1024][256] (262144)
#define OFF_QB     3156992    // bf16 [16][64][512] (262144 floats)
#define OFF_LGB    3419136    // bf16 [16][4096][64] (2097152 floats)
// total = 5516288 floats = 22.1 MB

__device__ __forceinline__ unsigned short f2bf(float f) {
    unsigned int u = __float_as_uint(f);
    u += 0x7fffu + ((u >> 16) & 1u);   // round-to-nearest-even
    return (unsigned short)(u >> 16);
}

// ---- K1: pooling partials. grid 1024 (b*64+nc), block 256 ----
__global__ __launch_bounds__(256) void k_pool(const float* __restrict__ X, float* __restrict__ ws) {
    int b = blockIdx.x >> 6, nc = blockIdx.x & 63, t = threadIdx.x;
    int c = t & 127, p = t >> 7;
    const float4* X4 = (const float4*)X;
    float4 s = make_float4(0.f, 0.f, 0.f, 0.f);
    float4 mx = make_float4(-INFINITY, -INFINITY, -INFINITY, -INFINITY);
    int rowbase = b * N_ + nc * 64 + p;
#pragma unroll 8
    for (int i = 0; i < 32; i++) {
        int n = rowbase + 2 * i;
        float4 v = X4[n * 128 + c];
        s.x += v.x; s.y += v.y; s.z += v.z; s.w += v.w;
        mx.x = fmaxf(mx.x, v.x); mx.y = fmaxf(mx.y, v.y);
        mx.z = fmaxf(mx.z, v.z); mx.w = fmaxf(mx.w, v.w);
    }
    int slot = (b * 128 + nc * 2 + p) * 128 + c;   // float4 units
    ((float4*)(ws + OFF_PSUM))[slot] = s;
    ((float4*)(ws + OFF_PMAXP))[slot] = mx;
}

// ---- K1b: finalize ctx -> bf16 [b][1024]. grid 64 (b*4+quadrant), block 256 ----
// quadrant q: k4 in [q*64, q*64+64); q<2 -> mean-half, q>=2 -> max-half.
// wave w reduces c in [w*32, w*32+32), lane = k4 offset -> coalesced loads.
__global__ __launch_bounds__(256) void k_ctx(float* __restrict__ ws) {
    __shared__ f32x4 red[256];
    int b = blockIdx.x >> 2, q = blockIdx.x & 3, t = threadIdx.x;
    int lane = t & 63, w = t >> 6;
    bool isMax = (q >= 2);
    const f32x4* SRC = (const f32x4*)(ws + (isMax ? OFF_PMAXP : OFF_PSUM));
    int kk = (q & 1) * 64 + lane;           // float4-col within the 128-wide array
    f32x4 acc;
    if (isMax) acc = (f32x4){-INFINITY, -INFINITY, -INFINITY, -INFINITY};
    else       acc = (f32x4){0.f, 0.f, 0.f, 0.f};
#pragma unroll 8
    for (int i = 0; i < 32; i++) {
        int c = w * 32 + i;
        f32x4 v = SRC[(b * 128 + c) * 128 + kk];
        if (isMax) {
            acc[0] = fmaxf(acc[0], v[0]); acc[1] = fmaxf(acc[1], v[1]);
            acc[2] = fmaxf(acc[2], v[2]); acc[3] = fmaxf(acc[3], v[3]);
        } else {
            acc[0] += v[0]; acc[1] += v[1]; acc[2] += v[2]; acc[3] += v[3];
        }
    }
    red[t] = acc;
    __syncthreads();
    if (t < 64) {
        f32x4 a = red[t], b1 = red[64 + t], c1 = red[128 + t], d = red[192 + t];
        f32x4 r;
        if (isMax) {
#pragma unroll
            for (int j = 0; j < 4; j++) r[j] = fmaxf(fmaxf(a[j], b1[j]), fmaxf(c1[j], d[j]));
        } else {
#pragma unroll
            for (int j = 0; j < 4; j++) r[j] = (a[j] + b1[j] + c1[j] + d[j]) * (1.0f / 4096.0f);
        }
        ushort4 o;
        o.x = f2bf(r[0]); o.y = f2bf(r[1]); o.z = f2bf(r[2]); o.w = f2bf(r[3]);
        ((ushort4*)(ws + OFF_CTXB))[b * 256 + q * 64 + t] = o;
    }
}

// ---- K2: P via MFMA: A=ctx, B=W rows -> C[b][r]. grid 512, block 256 ----
// W_ctx loads are NON-TEMPORAL: read-once stream; keep X resident in L3 for k_logits.
__global__ __launch_bounds__(256) void k_protos(const float* __restrict__ Wc, const float* __restrict__ pb,
                                                const float* __restrict__ bc, float* __restrict__ ws) {
    int t = threadIdx.x;
    int wave = blockIdx.x * 4 + (t >> 6);   // 0..2047 tiles of 16 W-rows
    int l = t & 63;
    int r0 = wave * 16;
    int row = r0 + (l & 15);                // this lane's W-row (B-frag col)
    int kg = l >> 4;
    const f32x4* W4 = (const f32x4*)Wc;                    // row stride 256 float4
    const short8* CB8 = (const short8*)(ws + OFF_CTXB);    // [16][128] short8 units
    f32x4 acc = (f32x4){0.f, 0.f, 0.f, 0.f};
    int wb = row * 256 + kg * 2;            // float4 idx: k = kg*8
    int cbase = (l & 15) * 128 + kg;        // A-frag: lane&15 = batch row
#pragma unroll 8
    for (int kc = 0; kc < 32; kc++) {
        f32x4 xa = __builtin_nontemporal_load(W4 + wb + kc * 8);
        f32x4 xb = __builtin_nontemporal_load(W4 + wb + kc * 8 + 1);
        short8 wf;
        wf[0] = (short)f2bf(xa[0]); wf[1] = (short)f2bf(xa[1]);
        wf[2] = (short)f2bf(xa[2]); wf[3] = (short)f2bf(xa[3]);
        wf[4] = (short)f2bf(xb[0]); wf[5] = (short)f2bf(xb[1]);
        wf[6] = (short)f2bf(xb[2]); wf[7] = (short)f2bf(xb[3]);
        short8 cf = CB8[cbase + kc * 4];
        acc = __builtin_amdgcn_mfma_f32_16x16x32_bf16(cf, wf, acc, 0, 0, 0);  // A=ctx, B=W
    }
    int r = r0 + (l & 15);
    float add = pb[r] + bc[r];
#pragma unroll
    for (int i = 0; i < 4; i++) {
        int bb = kg * 4 + i;
        ws[OFF_P + bb * MD + r] = acc[i] + add;   // 16 lanes -> 64B contiguous
    }
}

// ---- K3: Q'[b] = P[b] @ W_pre / 64 (bf16 out) + c' fold. grid 512, block 256 ----
__global__ __launch_bounds__(256) void k_q(const float* __restrict__ Wp, const float* __restrict__ bpre,
                                           float* __restrict__ ws) {
    __shared__ float4 lds4[512];            // P rows m0..m0+3
    int bx = blockIdx.x;
    int b = bx >> 5, mg = (bx >> 1) & 15, ch = bx & 1;
    int m0 = mg * 4, t = threadIdx.x;
    const float4* P4 = (const float4*)(ws + OFF_P + b * MD + m0 * 512);
    lds4[t] = P4[t];
    lds4[t + 256] = P4[t + 256];
    __syncthreads();
    if (ch == 0) {                          // fold c'[b][m0..m0+3]
        int w = t >> 6, l = t & 63;
        const float4* bp4 = (const float4*)bpre;
        float4 p0 = lds4[w * 128 + l * 2],     q0 = bp4[l * 2];
        float4 p1 = lds4[w * 128 + l * 2 + 1], q1 = bp4[l * 2 + 1];
        float s = p0.x * q0.x + p0.y * q0.y + p0.z * q0.z + p0.w * q0.w
                + p1.x * q1.x + p1.y * q1.y + p1.z * q1.z + p1.w * q1.w;
#pragma unroll
        for (int off = 1; off < 64; off <<= 1) s += __shfl_xor(s, off);
        if (l == 0) ws[OFF_CB + b * 64 + m0 + w] = s * (1.0f / 64.0f);
    }
    int col = ch * 256 + t;
    const float* W = Wp + col;
    float acc0 = 0.f, acc1 = 0.f, acc2 = 0.f, acc3 = 0.f;
#pragma unroll 8
    for (int j4 = 0; j4 < 128; j4++) {
        float4 p0 = lds4[j4];
        float4 p1 = lds4[128 + j4];
        float4 p2 = lds4[256 + j4];
        float4 p3 = lds4[384 + j4];
        float w0 = W[(4 * j4 + 0) * 512];
        float w1 = W[(4 * j4 + 1) * 512];
        float w2 = W[(4 * j4 + 2) * 512];
        float w3 = W[(4 * j4 + 3) * 512];
        acc0 += p0.x * w0 + p0.y * w1 + p0.z * w2 + p0.w * w3;
        acc1 += p1.x * w0 + p1.y * w1 + p1.z * w2 + p1.w * w3;
        acc2 += p2.x * w0 + p2.y * w1 + p2.z * w2 + p2.w * w3;
        acc3 += p3.x * w0 + p3.y * w1 + p3.z * w2 + p3.w * w3;
    }
    unsigned short* Qb = (unsigned short*)(ws + OFF_QB);
    int qb = (b * 64 + m0) * 512 + col;
    Qb[qb]        = f2bf(acc0 * (1.0f / 64.0f));
    Qb[qb + 512]  = f2bf(acc1 * (1.0f / 64.0f));
    Qb[qb + 1024] = f2bf(acc2 * (1.0f / 64.0f));
    Qb[qb + 1536] = f2bf(acc3 * (1.0f / 64.0f));
}

// ---- K4: logits = X.Q'^T + c' via bf16 MFMA; LG stored bf16. grid 1024, block 256 ----
__global__ __launch_bounds__(256) void k_logits(const float* __restrict__ X, float* __restrict__ ws) {
    int t = threadIdx.x;
    int W = blockIdx.x * 4 + (t >> 6);   // wave id 0..4095
    int b = W >> 8, nt = W & 255;        // batch, n-tile (16 rows)
    int l = t & 63, col = l & 15, kg = l >> 4;
    int nA = nt * 16 + col;              // A-fragment row
    const float4* X4 = (const float4*)X;
    const short8* Qb8 = (const short8*)(ws + OFF_QB);
    f32x4 acc[4];
#pragma unroll
    for (int mt = 0; mt < 4; mt++) acc[mt] = (f32x4){0.f, 0.f, 0.f, 0.f};

    int xbase4 = ((b * N_ + nA) * D_) >> 2;
    int qbase8 = b * 4096 + col * 64 + kg;  // (b*64+m)*64 short8-units, m = mt*16+col
#pragma unroll 2
    for (int kc = 0; kc < 16; kc++) {
        float4 xa = X4[xbase4 + kc * 8 + kg * 2];
        float4 xb = X4[xbase4 + kc * 8 + kg * 2 + 1];
        short8 af;
        af[0] = (short)f2bf(xa.x); af[1] = (short)f2bf(xa.y);
        af[2] = (short)f2bf(xa.z); af[3] = (short)f2bf(xa.w);
        af[4] = (short)f2bf(xb.x); af[5] = (short)f2bf(xb.y);
        af[6] = (short)f2bf(xb.z); af[7] = (short)f2bf(xb.w);
#pragma unroll
        for (int mt = 0; mt < 4; mt++) {
            short8 bfr = Qb8[qbase8 + mt * 1024 + kc * 4];
            acc[mt] = __builtin_amdgcn_mfma_f32_16x16x32_bf16(af, bfr, acc[mt], 0, 0, 0);
        }
    }
    const float* cb = ws + OFF_CB + b * 64;
    unsigned short* LGB = (unsigned short*)(ws + OFF_LGB) + b * (N_ * 64) + nt * 16 * 64;
#pragma unroll
    for (int mt = 0; mt < 4; mt++) {
        int m = mt * 16 + col;
        float c = cb[m];
        float v0 = acc[mt][0] + c, v1 = acc[mt][1] + c;
        float v2 = acc[mt][2] + c, v3 = acc[mt][3] + c;
        int nr = kg * 4;
        LGB[(nr + 0) * 64 + m] = f2bf(v0);
        LGB[(nr + 1) * 64 + m] = f2bf(v1);
        LGB[(nr + 2) * 64 + m] = f2bf(v2);
        LGB[(nr + 3) * 64 + m] = f2bf(v3);
        float mx = fmaxf(fmaxf(v0, v1), fmaxf(v2, v3));
        mx = fmaxf(mx, __shfl_xor(mx, 16));
        mx = fmaxf(mx, __shfl_xor(mx, 32));
        float s = expf(v0 - mx) + expf(v1 - mx) + expf(v2 - mx) + expf(v3 - mx);
        s += __shfl_xor(s, 16);
        s += __shfl_xor(s, 32);
        if (kg == 0) {
            ws[OFF_TPMAX + (b * 64 + m) * 256 + nt] = mx;
            ws[OFF_TPSUM + (b * 64 + m) * 256 + nt] = s;
        }
    }
}

// ---- K5: combine partials -> gmax, 1/denom. wave per (b,m). grid 256, block 256 ----
__global__ __launch_bounds__(256) void k_combine(float* __restrict__ ws) {
    int t = threadIdx.x;
    int w = blockIdx.x * 4 + (t >> 6);   // 0..1023 = b*64+m
    int l = t & 63;
    float4 a  = ((const float4*)(ws + OFF_TPMAX + w * 256))[l];
    float4 s4 = ((const float4*)(ws + OFF_TPSUM + w * 256))[l];
    float g = fmaxf(fmaxf(a.x, a.y), fmaxf(a.z, a.w));
    float s = s4.x * expf(a.x - g) + s4.y * expf(a.y - g)
            + s4.z * expf(a.z - g) + s4.w * expf(a.w - g);
#pragma unroll
    for (int off = 1; off < 64; off <<= 1) {
        float og = __shfl_xor(g, off);
        float os = __shfl_xor(s, off);
        float ng = fmaxf(g, og);
        s = s * expf(g - ng) + os * expf(og - ng);
        g = ng;
    }
    if (l == 0) { ws[OFF_GMAX + w] = g; ws[OFF_GINV + w] = 1.0f / s; }
}

// ---- K6: out = exp(bf16(l) - gmax) * ginv. grid 2048, block 256 (8 elems/thread) ----
__global__ __launch_bounds__(256) void k_final(const float* __restrict__ ws, float* __restrict__ out) {
    int idx = blockIdx.x * 256 + threadIdx.x;   // uint4 (8 bf16) index
    int flat = idx * 8;
    int b = flat >> 18;                         // / (4096*64)
    int m0 = flat & 63;                         // multiple of 8
    uint4 lg = ((const uint4*)((const unsigned short*)(ws + OFF_LGB)))[idx];
    int bm = b * 64 + m0;
    float4 ga = *(const float4*)(ws + OFF_GMAX + bm);
    float4 gb = *(const float4*)(ws + OFF_GMAX + bm + 4);
    float4 ia = *(const float4*)(ws + OFF_GINV + bm);
    float4 ib = *(const float4*)(ws + OFF_GINV + bm + 4);
    float4 o0, o1;
    o0.x = expf(__uint_as_float(lg.x << 16)         - ga.x) * ia.x;
    o0.y = expf(__uint_as_float(lg.x & 0xffff0000u) - ga.y) * ia.y;
    o0.z = expf(__uint_as_float(lg.y << 16)         - ga.z) * ia.z;
    o0.w = expf(__uint_as_float(lg.y & 0xffff0000u) - ga.w) * ia.w;
    o1.x = expf(__uint_as_float(lg.z << 16)         - gb.x) * ib.x;
    o1.y = expf(__uint_as_float(lg.z & 0xffff0000u) - gb.y) * ib.y;
    o1.z = expf(__uint_as_float(lg.w << 16)         - gb.z) * ib.z;
    o1.w = expf(__uint_as_float(lg.w & 0xffff0000u) - gb.w) * ib.w;
    ((float4*)out)[idx * 2]     = o0;
    ((float4*)out)[idx * 2 + 1] = o1;
}

extern "C" void kernel_launch(void* const* d_in, const int* in_sizes, int n_in,
                              void* d_out, int out_size, void* d_ws, size_t ws_size,
                              hipStream_t stream) {
    const float* X  = (const float*)d_in[0];
    const float* pb = (const float*)d_in[1];
    const float* Wc = (const float*)d_in[2];
    const float* bc = (const float*)d_in[3];
    const float* Wp = (const float*)d_in[4];
    const float* bp = (const float*)d_in[5];
    float* ws  = (float*)d_ws;
    float* out = (float*)d_out;

    k_pool<<<1024, 256, 0, stream>>>(X, ws);
    k_ctx<<<64, 256, 0, stream>>>(ws);
    k_protos<<<512, 256, 0, stream>>>(Wc, pb, bc, ws);
    k_q<<<512, 256, 0, stream>>>(Wp, bp, ws);
    k_logits<<<1024, 256, 0, stream>>>(X, ws);
    k_combine<<<256, 256, 0, stream>>>(ws);
    k_final<<<2048, 256, 0, stream>>>(ws, out);
}